// Round 1
// baseline (1293.696 us; speedup 1.0000x reference)
//
#include <hip/hip_runtime.h>
#include <math.h>

// Problem constants (fixed by reference):
#define BB 2
#define NN 2048
#define DD 512
#define HH 8
#define HD 64
#define KML 1000

typedef long long i64;

// ---------------------------------------------------------------------------
// Generic fp32 SGEMM: C[M,N] = A @ B + bias.  Tiles 128x128, BK=8, 256 thr,
// 8x8 micro-tile per thread (64 fmac per 16 LDS reads -> VALU-bound).
// ATRANS: A is [K,M] (used for v_seq = Wv2^T @ V_emb).
// BIAS_ROW: bias indexed by row (m) instead of col (n).
// ---------------------------------------------------------------------------
template<bool ATRANS, bool BIAS_ROW>
__global__ __launch_bounds__(256) void sgemm128(
    const float* __restrict__ A, const float* __restrict__ Bm,
    const float* __restrict__ bias, float* __restrict__ C,
    int M, int N, int K)
{
    __shared__ float As[8][132];   // [k][m], +4 pad keeps 16B align, breaks conflicts
    __shared__ float Bs[8][132];   // [k][n]
    const int t  = threadIdx.x;
    const int tx = t & 15, ty = t >> 4;
    const int m0 = blockIdx.y * 128, n0 = blockIdx.x * 128;

    float acc[8][8];
#pragma unroll
    for (int i = 0; i < 8; ++i)
#pragma unroll
        for (int j = 0; j < 8; ++j) acc[i][j] = 0.f;

    for (int k0 = 0; k0 < K; k0 += 8) {
        __syncthreads();
        if (!ATRANS) {
#pragma unroll
            for (int l = 0; l < 4; ++l) {
                int e = l * 256 + t;
                int row = e >> 3, col = e & 7;          // row=m, col=k
                As[col][row] = A[(i64)(m0 + row) * K + (k0 + col)];
            }
        } else {
#pragma unroll
            for (int l = 0; l < 4; ++l) {
                int e = l * 256 + t;
                int row = e >> 7, col = e & 127;        // row=k, col=m (coalesced)
                As[row][col] = A[(i64)(k0 + row) * M + (m0 + col)];
            }
        }
#pragma unroll
        for (int l = 0; l < 4; ++l) {
            int e = l * 256 + t;
            int row = e >> 7, col = e & 127;            // row=k, col=n (coalesced)
            Bs[row][col] = Bm[(i64)(k0 + row) * N + (n0 + col)];
        }
        __syncthreads();
#pragma unroll
        for (int k = 0; k < 8; ++k) {
            float a[8], b[8];
#pragma unroll
            for (int i = 0; i < 8; ++i) a[i] = As[k][ty * 8 + i];
#pragma unroll
            for (int j = 0; j < 8; ++j) b[j] = Bs[k][tx * 8 + j];
#pragma unroll
            for (int i = 0; i < 8; ++i)
#pragma unroll
                for (int j = 0; j < 8; ++j) acc[i][j] = fmaf(a[i], b[j], acc[i][j]);
        }
    }
#pragma unroll
    for (int i = 0; i < 8; ++i) {
        int m = m0 + ty * 8 + i;
#pragma unroll
        for (int j = 0; j < 8; ++j) {
            int n = n0 + tx * 8 + j;
            float bv = BIAS_ROW ? bias[m] : bias[n];
            C[(i64)m * N + n] = acc[i][j] + bv;
        }
    }
}

// ---------------------------------------------------------------------------
// S = (Q_h @ K_h^T) / 8, band-masked (|i-j|<=3 -> -inf), written as logits
// into the attn region of d_out.  Per (b,h): M=N=2048, K=64.
// ---------------------------------------------------------------------------
__global__ __launch_bounds__(256) void qk_logits(
    const float* __restrict__ qp, const float* __restrict__ kp,
    float* __restrict__ attn)
{
    __shared__ float As[8][132];   // [k][i]
    __shared__ float Bs[8][132];   // [k][j]
    const int t  = threadIdx.x;
    const int tx = t & 15, ty = t >> 4;
    const int bh = blockIdx.z, b = bh >> 3, h = bh & 7;
    const int i0 = blockIdx.y * 128, j0 = blockIdx.x * 128;
    const float* qb = qp + (i64)b * NN * DD + h * HD;
    const float* kb = kp + (i64)b * NN * DD + h * HD;

    float acc[8][8];
#pragma unroll
    for (int i = 0; i < 8; ++i)
#pragma unroll
        for (int j = 0; j < 8; ++j) acc[i][j] = 0.f;

    for (int k0 = 0; k0 < HD; k0 += 8) {
        __syncthreads();
#pragma unroll
        for (int l = 0; l < 4; ++l) {
            int e = l * 256 + t;
            int row = e >> 3, col = e & 7;              // row=i/j, col=k
            As[col][row] = qb[(i64)(i0 + row) * DD + (k0 + col)];
            Bs[col][row] = kb[(i64)(j0 + row) * DD + (k0 + col)];
        }
        __syncthreads();
#pragma unroll
        for (int k = 0; k < 8; ++k) {
            float a[8], b2[8];
#pragma unroll
            for (int i = 0; i < 8; ++i) a[i]  = As[k][ty * 8 + i];
#pragma unroll
            for (int j = 0; j < 8; ++j) b2[j] = Bs[k][tx * 8 + j];
#pragma unroll
            for (int i = 0; i < 8; ++i)
#pragma unroll
                for (int j = 0; j < 8; ++j) acc[i][j] = fmaf(a[i], b2[j], acc[i][j]);
        }
    }
    float* outp = attn + (i64)bh * NN * NN;
#pragma unroll
    for (int i = 0; i < 8; ++i) {
        int ii = i0 + ty * 8 + i;
#pragma unroll
        for (int j = 0; j < 8; ++j) {
            int jj = j0 + tx * 8 + j;
            int d = ii - jj;
            float s = (d >= -3 && d <= 3) ? -INFINITY : acc[i][j] * 0.125f;
            outp[(i64)ii * NN + jj] = s;
        }
    }
}

// ---------------------------------------------------------------------------
// Per-row softmax stats: one wave per row.  m = rowmax, lrow = 1/sum(exp).
// ---------------------------------------------------------------------------
__global__ __launch_bounds__(256) void row_stats(
    const float* __restrict__ attn, float* __restrict__ mrow,
    float* __restrict__ lrow)
{
    const int w = threadIdx.x >> 6, lane = threadIdx.x & 63;
    const i64 row = (i64)blockIdx.x * 4 + w;          // 0 .. B*H*N-1
    const float4* p = (const float4*)(attn + row * NN);
    float4 v[8];
#pragma unroll
    for (int it = 0; it < 8; ++it) v[it] = p[it * 64 + lane];

    float m = -INFINITY;
#pragma unroll
    for (int it = 0; it < 8; ++it)
        m = fmaxf(m, fmaxf(fmaxf(v[it].x, v[it].y), fmaxf(v[it].z, v[it].w)));
#pragma unroll
    for (int off = 32; off > 0; off >>= 1) m = fmaxf(m, __shfl_xor(m, off));

    float s = 0.f;
#pragma unroll
    for (int it = 0; it < 8; ++it) {
        s += expf(v[it].x - m);   // expf(-inf - m) == 0 for masked entries
        s += expf(v[it].y - m);
        s += expf(v[it].z - m);
        s += expf(v[it].w - m);
    }
#pragma unroll
    for (int off = 32; off > 0; off >>= 1) s += __shfl_xor(s, off);

    if (lane == 0) { mrow[row] = m; lrow[row] = 1.f / s; }
}

// ---------------------------------------------------------------------------
// Normalize + PV in one pass over the attn region.
// Per (b,h, 128-row tile): reads logits, writes p = exp(s-m)/l back,
// accumulates C[128,64] = P[128,2048] @ V_h[2048,64] into hout[b,n,h*64+d].
// ---------------------------------------------------------------------------
__global__ __launch_bounds__(256) void pv_norm(
    float* __restrict__ attn, const float* __restrict__ mrow,
    const float* __restrict__ lrow, const float* __restrict__ vseq,
    float* __restrict__ hout)
{
    __shared__ float Ps[32][132];  // [j][i] transposed for compute reads
    __shared__ float Vs[32][68];   // [j][d]
    __shared__ float ml[128], il[128];
    const int t  = threadIdx.x;
    const int tx = t & 15, ty = t >> 4;
    const int bh = blockIdx.z, b = bh >> 3, h = bh & 7;
    const int i0 = blockIdx.x * 128;
    float* Pg = attn + (i64)bh * NN * NN + (i64)i0 * NN;
    const float* Vg = vseq + h * HD;

    if (t < 128) {
        ml[t] = mrow[(i64)bh * NN + i0 + t];
        il[t] = lrow[(i64)bh * NN + i0 + t];
    }

    float acc[8][4];
#pragma unroll
    for (int i = 0; i < 8; ++i)
#pragma unroll
        for (int j = 0; j < 4; ++j) acc[i][j] = 0.f;

    for (int j0 = 0; j0 < NN; j0 += 32) {
        __syncthreads();
        // P tile: 128 rows x 32 cols = 1024 float4 / 256 thr = 4 each
#pragma unroll
        for (int l = 0; l < 4; ++l) {
            int e = l * 256 + t;
            int row = e >> 3, c4 = e & 7;
            float4* gp = (float4*)(Pg + (i64)row * NN + j0) + c4;
            float4 v = *gp;
            float m = ml[row], sc = il[row];
            v.x = expf(v.x - m) * sc;
            v.y = expf(v.y - m) * sc;
            v.z = expf(v.z - m) * sc;
            v.w = expf(v.w - m) * sc;
            *gp = v;                                  // final attn output
            int jc = c4 * 4;
            Ps[jc + 0][row] = v.x;
            Ps[jc + 1][row] = v.y;
            Ps[jc + 2][row] = v.z;
            Ps[jc + 3][row] = v.w;
        }
        // V tile: 32 rows x 64 = 512 float4 / 256 thr = 2 each
#pragma unroll
        for (int l = 0; l < 2; ++l) {
            int e = l * 256 + t;
            int row = e >> 4, c4 = e & 15;
            float4 v = *((const float4*)(Vg + (i64)(j0 + row) * DD) + c4);
            int dc = c4 * 4;
            Vs[row][dc + 0] = v.x;
            Vs[row][dc + 1] = v.y;
            Vs[row][dc + 2] = v.z;
            Vs[row][dc + 3] = v.w;
        }
        __syncthreads();
#pragma unroll
        for (int k = 0; k < 32; ++k) {
            float a[8], b2[4];
#pragma unroll
            for (int i = 0; i < 8; ++i) a[i]  = Ps[k][ty * 8 + i];
#pragma unroll
            for (int j = 0; j < 4; ++j) b2[j] = Vs[k][tx * 4 + j];
#pragma unroll
            for (int i = 0; i < 8; ++i)
#pragma unroll
                for (int j = 0; j < 4; ++j) acc[i][j] = fmaf(a[i], b2[j], acc[i][j]);
        }
    }
#pragma unroll
    for (int i = 0; i < 8; ++i)
#pragma unroll
        for (int j = 0; j < 4; ++j)
            hout[(i64)(b * NN + i0 + ty * 8 + i) * DD + h * HD + tx * 4 + j] =
                acc[i][j];
}

// ---------------------------------------------------------------------------
extern "C" void kernel_launch(void* const* d_in, const int* in_sizes, int n_in,
                              void* d_out, int out_size, void* d_ws, size_t ws_size,
                              hipStream_t stream)
{
    const float* q    = (const float*)d_in[0];
    const float* k    = (const float*)d_in[1];
    // d_in[2] = v : unused by the reference module
    const float* Wq   = (const float*)d_in[3];
    const float* bq   = (const float*)d_in[4];
    const float* Wk   = (const float*)d_in[5];
    const float* bk   = (const float*)d_in[6];
    const float* Vemb = (const float*)d_in[7];
    const float* Wv2  = (const float*)d_in[8];
    const float* bv2  = (const float*)d_in[9];
    const float* Wout = (const float*)d_in[10];
    const float* bout = (const float*)d_in[11];

    float* outp = (float*)d_out;                   // [2,2048,512]
    float* attn = outp + (i64)BB * NN * DD;        // [2,8,2048,2048]

    // workspace layout (~30 MB of fp32)
    float* ws   = (float*)d_ws;
    float* qp   = ws;                              // 4096*512
    float* kp   = qp + 4096 * 512;                 // 4096*512
    float* vs   = kp + 4096 * 512;                 // 2048*512
    float* mrow = vs + 2048 * 512;                 // 32768
    float* lrow = mrow + 32768;                    // 32768
    float* hout = lrow + 32768;                    // 4096*512

    // projections
    sgemm128<false, false><<<dim3(4, 32), 256, 0, stream>>>(q, Wq, bq, qp, 4096, 512, 512);
    sgemm128<false, false><<<dim3(4, 32), 256, 0, stream>>>(k, Wk, bk, kp, 4096, 512, 512);
    // v_seq[s,d] = sum_m Wv2[m,s] * V_emb[m,d] + bv2[s]
    sgemm128<true, true><<<dim3(4, 16), 256, 0, stream>>>(Wv2, Vemb, bv2, vs, 2048, 512, KML);
    // attention
    qk_logits<<<dim3(16, 16, 16), 256, 0, stream>>>(qp, kp, attn);
    row_stats<<<dim3(8192), 256, 0, stream>>>(attn, mrow, lrow);
    pv_norm<<<dim3(16, 1, 16), 256, 0, stream>>>(attn, mrow, lrow, vs, hout);
    // output projection
    sgemm128<false, false><<<dim3(4, 32), 256, 0, stream>>>(hout, Wout, bout, outp, 4096, 512, 512);
}

// Round 2
// 1284.406 us; speedup vs baseline: 1.0072x; 1.0072x over previous
//
#include <hip/hip_runtime.h>
#include <math.h>

#define BB 2
#define NN 2048
#define DD 512
#define HH 8
#define HD 64
#define KML 1000

typedef long long i64;

// ---------------------------------------------------------------------------
// fp32 SGEMM: C[M,N] = A @ B + bias.  64x64 tiles, BK=16, 256 thr, 4x4 micro.
// ATRANS: A is [K,M].  BIAS_ROW: bias indexed by m.
// ---------------------------------------------------------------------------
template<bool ATRANS, bool BIAS_ROW>
__global__ __launch_bounds__(256) void sgemm64(
    const float* __restrict__ A, const float* __restrict__ Bm,
    const float* __restrict__ bias, float* __restrict__ C,
    int M, int N, int K)
{
    __shared__ float As[16][68];   // [k][m]
    __shared__ float Bs[16][68];   // [k][n]
    const int t  = threadIdx.x;
    const int tx = t & 15, ty = t >> 4;
    const int m0 = blockIdx.y * 64, n0 = blockIdx.x * 64;

    float acc[4][4];
#pragma unroll
    for (int i = 0; i < 4; ++i)
#pragma unroll
        for (int j = 0; j < 4; ++j) acc[i][j] = 0.f;

    for (int k0 = 0; k0 < K; k0 += 16) {
        __syncthreads();
        if (!ATRANS) {
            int m = t >> 2, k4 = t & 3;                 // 64 x 4-float4
            float4 v = *((const float4*)(A + (i64)(m0 + m) * K + k0) + k4);
            As[k4 * 4 + 0][m] = v.x; As[k4 * 4 + 1][m] = v.y;
            As[k4 * 4 + 2][m] = v.z; As[k4 * 4 + 3][m] = v.w;
        } else {
            int k = t >> 4, m4 = t & 15;                // 16 x 16-float4
            float4 v;
            if (k0 + k < K) v = *((const float4*)(A + (i64)(k0 + k) * M + m0) + m4);
            else            v = make_float4(0.f, 0.f, 0.f, 0.f);
            As[k][m4 * 4 + 0] = v.x; As[k][m4 * 4 + 1] = v.y;
            As[k][m4 * 4 + 2] = v.z; As[k][m4 * 4 + 3] = v.w;
        }
        {
            int k = t >> 4, n4 = t & 15;
            float4 v;
            if (k0 + k < K) v = *((const float4*)(Bm + (i64)(k0 + k) * N + n0) + n4);
            else            v = make_float4(0.f, 0.f, 0.f, 0.f);
            Bs[k][n4 * 4 + 0] = v.x; Bs[k][n4 * 4 + 1] = v.y;
            Bs[k][n4 * 4 + 2] = v.z; Bs[k][n4 * 4 + 3] = v.w;
        }
        __syncthreads();
#pragma unroll
        for (int k = 0; k < 16; ++k) {
            float4 a = *(const float4*)&As[k][ty * 4];
            float4 b = *(const float4*)&Bs[k][tx * 4];
            float av[4] = {a.x, a.y, a.z, a.w};
            float bv[4] = {b.x, b.y, b.z, b.w};
#pragma unroll
            for (int i = 0; i < 4; ++i)
#pragma unroll
                for (int j = 0; j < 4; ++j) acc[i][j] = fmaf(av[i], bv[j], acc[i][j]);
        }
    }
#pragma unroll
    for (int i = 0; i < 4; ++i) {
        int m = m0 + ty * 4 + i;
        float4 o;
        if (BIAS_ROW) {
            float bv = bias[m];
            o = make_float4(acc[i][0] + bv, acc[i][1] + bv, acc[i][2] + bv, acc[i][3] + bv);
        } else {
            const float* bp = bias + n0 + tx * 4;
            o = make_float4(acc[i][0] + bp[0], acc[i][1] + bp[1],
                            acc[i][2] + bp[2], acc[i][3] + bp[3]);
        }
        *((float4*)(C + (i64)m * N + n0 + tx * 4)) = o;
    }
}

// ---------------------------------------------------------------------------
// Fused QK^T/8 + band mask + online row stats.
// Block: 32 rows x full 2048 cols per (b,h).  Writes logits S into attn
// region, and per-row (max, 1/sumexp) to mrow/ilrow.
// Grid: (NN/32, B*H) = (64, 16) = 1024 blocks.
// ---------------------------------------------------------------------------
__global__ __launch_bounds__(256) void qk_stats(
    const float* __restrict__ qp, const float* __restrict__ kp,
    float* __restrict__ attn, float* __restrict__ mrow,
    float* __restrict__ ilrow)
{
    __shared__ float Qs[64][36];    // [k][i]  (2304 floats; reused for reduce)
    __shared__ float Ks[64][132];   // [k][j]
    float* redm = &Qs[0][0];        // 32*33
    float* redl = &Qs[0][0] + 32 * 33;
    const int t  = threadIdx.x;
    const int tx = t & 31, ty = t >> 5;
    const int bh = blockIdx.y, b = bh >> 3, h = bh & 7;
    const int i0 = blockIdx.x * 32;
    const float* qb = qp + (i64)b * NN * DD + h * HD;
    const float* kb = kp + (i64)b * NN * DD + h * HD;
    float* Sg = attn + (i64)bh * NN * NN;

    // load Q rows: 32 x 64 = 512 float4, 2/thread
#pragma unroll
    for (int l = 0; l < 2; ++l) {
        int e = l * 256 + t;
        int i = e >> 4, k4 = e & 15;
        float4 v = *((const float4*)(qb + (i64)(i0 + i) * DD) + k4);
        Qs[k4 * 4 + 0][i] = v.x; Qs[k4 * 4 + 1][i] = v.y;
        Qs[k4 * 4 + 2][i] = v.z; Qs[k4 * 4 + 3][i] = v.w;
    }

    float mt[4], lt[4];
#pragma unroll
    for (int i = 0; i < 4; ++i) { mt[i] = -1e30f; lt[i] = 0.f; }

    for (int j0 = 0; j0 < NN; j0 += 128) {
        __syncthreads();
        // K tile: 128 x 64 = 2048 float4, 8/thread
#pragma unroll
        for (int l = 0; l < 8; ++l) {
            int e = l * 256 + t;
            int j = e >> 4, k4 = e & 15;
            float4 v = *((const float4*)(kb + (i64)(j0 + j) * DD) + k4);
            Ks[k4 * 4 + 0][j] = v.x; Ks[k4 * 4 + 1][j] = v.y;
            Ks[k4 * 4 + 2][j] = v.z; Ks[k4 * 4 + 3][j] = v.w;
        }
        __syncthreads();

        float acc[4][4];
#pragma unroll
        for (int i = 0; i < 4; ++i)
#pragma unroll
            for (int j = 0; j < 4; ++j) acc[i][j] = 0.f;
#pragma unroll
        for (int k = 0; k < 64; ++k) {
            float4 a = *(const float4*)&Qs[k][ty * 4];
            float4 b2 = *(const float4*)&Ks[k][tx * 4];
            float av[4] = {a.x, a.y, a.z, a.w};
            float bv[4] = {b2.x, b2.y, b2.z, b2.w};
#pragma unroll
            for (int i = 0; i < 4; ++i)
#pragma unroll
                for (int j = 0; j < 4; ++j) acc[i][j] = fmaf(av[i], bv[j], acc[i][j]);
        }
        // scale + band mask + online stats + store
#pragma unroll
        for (int i = 0; i < 4; ++i) {
            int ii = i0 + ty * 4 + i;
            float s[4];
#pragma unroll
            for (int j = 0; j < 4; ++j) {
                int jj = j0 + tx * 4 + j;
                int d = ii - jj;
                s[j] = (d >= -3 && d <= 3) ? -INFINITY : acc[i][j] * 0.125f;
            }
            float tm = fmaxf(fmaxf(s[0], s[1]), fmaxf(s[2], s[3]));
            float M2 = fmaxf(mt[i], tm);
            lt[i] = lt[i] * expf(mt[i] - M2) +
                    expf(s[0] - M2) + expf(s[1] - M2) +
                    expf(s[2] - M2) + expf(s[3] - M2);
            mt[i] = M2;
            float4 o = make_float4(s[0], s[1], s[2], s[3]);
            *((float4*)(Sg + (i64)ii * NN + j0 + tx * 4)) = o;
        }
    }
    // block-level (m,l) reduce across the 32 col-threads of each row
    __syncthreads();
#pragma unroll
    for (int i = 0; i < 4; ++i) {
        int row = ty * 4 + i;
        redm[row * 33 + tx] = mt[i];
        redl[row * 33 + tx] = lt[i];
    }
    __syncthreads();
    if (t < 32) {
        float M = -1e30f, L = 0.f;
        for (int x = 0; x < 32; ++x) {
            float m2 = redm[t * 33 + x], l2 = redl[t * 33 + x];
            float M2 = fmaxf(M, m2);
            L = L * expf(M - M2) + l2 * expf(m2 - M2);
            M = M2;
        }
        mrow[(i64)bh * NN + i0 + t]  = M;
        ilrow[(i64)bh * NN + i0 + t] = 1.f / L;
    }
}

// ---------------------------------------------------------------------------
// Normalize S -> P (in place, final attn output) + PV.
// Block: 64 rows x full 2048 cols per (b,h).  C tile 64x64, 4x4 micro.
// Grid: (NN/64, B*H) = (32, 16) = 512 blocks.
// ---------------------------------------------------------------------------
__global__ __launch_bounds__(256) void pv_norm64(
    float* __restrict__ attn, const float* __restrict__ mrow,
    const float* __restrict__ ilrow, const float* __restrict__ vseq,
    float* __restrict__ hout)
{
    __shared__ float Ps[64][68];   // [j][i]
    __shared__ float Vs[64][68];   // [j][d]
    __shared__ float ml[64], il[64];
    const int t  = threadIdx.x;
    const int tx = t & 15, ty = t >> 4;
    const int bh = blockIdx.y, b = bh >> 3, h = bh & 7;
    const int i0 = blockIdx.x * 64;
    float* Pg = attn + (i64)bh * NN * NN + (i64)i0 * NN;
    const float* Vg = vseq + h * HD;

    if (t < 64) {
        ml[t] = mrow[(i64)bh * NN + i0 + t];
        il[t] = ilrow[(i64)bh * NN + i0 + t];
    }

    float acc[4][4];
#pragma unroll
    for (int i = 0; i < 4; ++i)
#pragma unroll
        for (int j = 0; j < 4; ++j) acc[i][j] = 0.f;

    for (int j0 = 0; j0 < NN; j0 += 64) {
        __syncthreads();
        // P chunk: 64 rows x 64 cols = 1024 float4, 4/thread (normalize + writeback)
#pragma unroll
        for (int l = 0; l < 4; ++l) {
            int e = l * 256 + t;
            int row = e >> 4, c4 = e & 15;
            float4* gp = (float4*)(Pg + (i64)row * NN + j0) + c4;
            float4 v = *gp;
            float m = ml[row], sc = il[row];
            v.x = expf(v.x - m) * sc;
            v.y = expf(v.y - m) * sc;
            v.z = expf(v.z - m) * sc;
            v.w = expf(v.w - m) * sc;
            *gp = v;                                   // final attn value
            Ps[c4 * 4 + 0][row] = v.x; Ps[c4 * 4 + 1][row] = v.y;
            Ps[c4 * 4 + 2][row] = v.z; Ps[c4 * 4 + 3][row] = v.w;
        }
        // V chunk: 64 x 64 = 1024 float4, 4/thread
#pragma unroll
        for (int l = 0; l < 4; ++l) {
            int e = l * 256 + t;
            int row = e >> 4, c4 = e & 15;
            float4 v = *((const float4*)(Vg + (i64)(j0 + row) * DD) + c4);
            Vs[row][c4 * 4 + 0] = v.x; Vs[row][c4 * 4 + 1] = v.y;
            Vs[row][c4 * 4 + 2] = v.z; Vs[row][c4 * 4 + 3] = v.w;
        }
        __syncthreads();
#pragma unroll
        for (int k = 0; k < 64; ++k) {
            float4 a = *(const float4*)&Ps[k][ty * 4];
            float4 b2 = *(const float4*)&Vs[k][tx * 4];
            float av[4] = {a.x, a.y, a.z, a.w};
            float bv[4] = {b2.x, b2.y, b2.z, b2.w};
#pragma unroll
            for (int i = 0; i < 4; ++i)
#pragma unroll
                for (int j = 0; j < 4; ++j) acc[i][j] = fmaf(av[i], bv[j], acc[i][j]);
        }
    }
#pragma unroll
    for (int i = 0; i < 4; ++i) {
        float4 o = make_float4(acc[i][0], acc[i][1], acc[i][2], acc[i][3]);
        *((float4*)(hout + (i64)(b * NN + i0 + ty * 4 + i) * DD + h * HD + tx * 4)) = o;
    }
}

// ---------------------------------------------------------------------------
extern "C" void kernel_launch(void* const* d_in, const int* in_sizes, int n_in,
                              void* d_out, int out_size, void* d_ws, size_t ws_size,
                              hipStream_t stream)
{
    const float* q    = (const float*)d_in[0];
    const float* k    = (const float*)d_in[1];
    const float* Wq   = (const float*)d_in[3];
    const float* bq   = (const float*)d_in[4];
    const float* Wk   = (const float*)d_in[5];
    const float* bk   = (const float*)d_in[6];
    const float* Vemb = (const float*)d_in[7];
    const float* Wv2  = (const float*)d_in[8];
    const float* bv2  = (const float*)d_in[9];
    const float* Wout = (const float*)d_in[10];
    const float* bout = (const float*)d_in[11];

    float* outp = (float*)d_out;                   // [2,2048,512]
    float* attn = outp + (i64)BB * NN * DD;        // [2,8,2048,2048]

    float* ws   = (float*)d_ws;
    float* qp   = ws;                              // 4096*512
    float* kp   = qp + 4096 * 512;                 // 4096*512
    float* vs   = kp + 4096 * 512;                 // 2048*512
    float* mrow = vs + 2048 * 512;                 // 32768
    float* lrow = mrow + 32768;                    // 32768
    float* hout = lrow + 32768;                    // 4096*512

    sgemm64<false, false><<<dim3(8, 64), 256, 0, stream>>>(q, Wq, bq, qp, 4096, 512, 512);
    sgemm64<false, false><<<dim3(8, 64), 256, 0, stream>>>(k, Wk, bk, kp, 4096, 512, 512);
    sgemm64<true,  true ><<<dim3(8, 32), 256, 0, stream>>>(Wv2, Vemb, bv2, vs, 2048, 512, KML);
    qk_stats<<<dim3(64, 16), 256, 0, stream>>>(qp, kp, attn, mrow, lrow);
    pv_norm64<<<dim3(32, 16), 256, 0, stream>>>(attn, mrow, lrow, vs, hout);
    sgemm64<false, false><<<dim3(8, 64), 256, 0, stream>>>(hout, Wout, bout, outp, 4096, 512, 512);
}